// Round 1
// baseline (2161.725 us; speedup 1.0000x reference)
//
#include <hip/hip_runtime.h>

// Problem constants
// B=2, T=2048, C=1024, H=16, D=64, MAXREL=32
// outputs: y [B,T,C] then att [B,H,T,T], both f32, concatenated in d_out.

// ---------------------------------------------------------------------------
// f32 SGEMM with bias: C[M,N] = A[M,K] @ B[K,N] + bias[N]
// 128x128 block, BK=16, 256 threads, 8x8 microtile (split 4+4 to avoid LDS
// bank conflicts: thread reads cols {tx*4..+3, 64+tx*4..+3}).
// ---------------------------------------------------------------------------
__global__ __launch_bounds__(256)
void sgemm_bias_kernel(const float* __restrict__ A, const float* __restrict__ B,
                       const float* __restrict__ bias, float* __restrict__ C,
                       int M, int N, int K) {
  __shared__ float As[16 * 128];  // transposed: As[k][m]
  __shared__ float Bs[16 * 128];  // Bs[k][n]
  const int tid = threadIdx.x;
  const int tx = tid & 15, ty = tid >> 4;
  const int bm = blockIdx.y * 128, bn = blockIdx.x * 128;

  float acc[8][8] = {{0.f}};

  for (int k0 = 0; k0 < K; k0 += 16) {
    // stage A tile (128 rows x 16 k), transposed into As[k][m]
    // stage B tile (16 rows x 128 cols)
#pragma unroll
    for (int j = 0; j < 2; ++j) {
      int f4 = tid + j * 256;
      int m = f4 >> 2, kq = (f4 & 3) << 2;
      float4 va = *(const float4*)&A[(size_t)(bm + m) * K + k0 + kq];
      As[(kq + 0) * 128 + m] = va.x;
      As[(kq + 1) * 128 + m] = va.y;
      As[(kq + 2) * 128 + m] = va.z;
      As[(kq + 3) * 128 + m] = va.w;
      int kr = f4 >> 5, c4 = (f4 & 31) << 2;
      *(float4*)&Bs[kr * 128 + c4] =
          *(const float4*)&B[(size_t)(k0 + kr) * N + bn + c4];
    }
    __syncthreads();
#pragma unroll
    for (int k = 0; k < 16; ++k) {
      float4 a0 = *(const float4*)&As[k * 128 + ty * 4];
      float4 a1 = *(const float4*)&As[k * 128 + 64 + ty * 4];
      float4 b0 = *(const float4*)&Bs[k * 128 + tx * 4];
      float4 b1 = *(const float4*)&Bs[k * 128 + 64 + tx * 4];
      float av[8] = {a0.x, a0.y, a0.z, a0.w, a1.x, a1.y, a1.z, a1.w};
      float bv[8] = {b0.x, b0.y, b0.z, b0.w, b1.x, b1.y, b1.z, b1.w};
#pragma unroll
      for (int i = 0; i < 8; ++i)
#pragma unroll
        for (int j = 0; j < 8; ++j)
          acc[i][j] = fmaf(av[i], bv[j], acc[i][j]);
    }
    __syncthreads();
  }

  // epilogue: bias add + store
#pragma unroll
  for (int i = 0; i < 8; ++i) {
    int mrow = bm + ((i < 4) ? (ty * 4 + i) : (64 + ty * 4 + i - 4));
#pragma unroll
    for (int jq = 0; jq < 2; ++jq) {
      int c = bn + jq * 64 + tx * 4;
      float4 o;
      o.x = acc[i][jq * 4 + 0] + bias[c + 0];
      o.y = acc[i][jq * 4 + 1] + bias[c + 1];
      o.z = acc[i][jq * 4 + 2] + bias[c + 2];
      o.w = acc[i][jq * 4 + 3] + bias[c + 3];
      *(float4*)&C[(size_t)mrow * N + c] = o;
    }
  }
}

// ---------------------------------------------------------------------------
// proj[b,h,q,r] = sum_d q[b,h,q,d] * rel_k_table[r,d]   (r in [0,65))
// 256 threads = 4 waves; one q-row per wave; lane r computes output r.
// rel table staged in LDS padded to stride 65 (conflict-free lane reads).
// ---------------------------------------------------------------------------
__global__ __launch_bounds__(256)
void relproj_kernel(const float* __restrict__ qkv, const float* __restrict__ tbl_g,
                    float* __restrict__ proj) {
  __shared__ float tbl[65 * 65];  // [r][d], stride 65
  __shared__ float qsh[4 * 64];
  const int tid = threadIdx.x;
  for (int i = tid; i < 65 * 64; i += 256) {
    int r = i >> 6, d = i & 63;
    tbl[r * 65 + d] = tbl_g[i];
  }
  const int w = tid >> 6, lane = tid & 63;
  const int rid = blockIdx.x * 4 + w;          // (b*16+h)*2048 + q
  const int b = rid >> 15, h = (rid >> 11) & 15, q = rid & 2047;
  qsh[w * 64 + lane] =
      qkv[(size_t)(b * 2048 + q) * 3072 + h * 64 + lane];
  __syncthreads();
  float acc = 0.f;
#pragma unroll
  for (int d = 0; d < 64; ++d)
    acc = fmaf(qsh[w * 64 + d], tbl[lane * 65 + d], acc);
  proj[(size_t)rid * 65 + lane] = acc;
  // r = 64 via wave reduction
  float part = qsh[w * 64 + lane] * tbl[64 * 65 + lane];
#pragma unroll
  for (int off = 32; off; off >>= 1) part += __shfl_xor(part, off, 64);
  if (lane == 0) proj[(size_t)rid * 65 + 64] = part;
}

// ---------------------------------------------------------------------------
// Fused causal attention for one (b,h,16-q-row block):
//  logits = (q@k^T + rel)/8 ; p = exp(logit) kept UNNORMALIZED in LDS row
//  tile [16][2048]; after full row: denom via wave reduce -> write normalized
//  att exactly once + accumulate y = (p@v)/denom.
// 512 threads = 8 waves; wave w owns rows 2w,2w+1; lane = k-col / v-dim.
// LDS: 16*2048*4 + 64*65*4 + 16*64*4 + 16*65*4 = 155,968 B (<=160 KiB).
// ---------------------------------------------------------------------------
__global__ __launch_bounds__(512)
void attn_kernel(const float* __restrict__ qkv, const float* __restrict__ proj,
                 float* __restrict__ att, float* __restrict__ ymid) {
  __shared__ float p_s[16 * 2048];
  __shared__ float kv_s[64 * 65];   // K tile then V tiles, stride 65
  __shared__ float qt[16 * 64];
  __shared__ float pj[16 * 65];
  const int tid = threadIdx.x;
  const int w = tid >> 6, lane = tid & 63;
  const int bh = blockIdx.y;               // b*16+h
  const int b = bh >> 4, h = bh & 15;
  const int q0 = blockIdx.x << 4;
  const size_t row_base = (size_t)(b * 2048) * 3072 + h * 64;

  for (int i = tid; i < 16 * 64; i += 512) {
    int r = i >> 6, d = i & 63;
    qt[i] = qkv[row_base + (size_t)(q0 + r) * 3072 + d];
  }
  {
    const float* psrc = &proj[((size_t)bh * 2048 + q0) * 65];
    for (int i = tid; i < 16 * 65; i += 512) pj[i] = psrc[i];
  }
  __syncthreads();

  const int r0 = w * 2, r1 = w * 2 + 1;
  const int qg0 = q0 + r0, qg1 = q0 + r1;
  const int nkt = (q0 + 15) / 64 + 1;  // tiles overlapping causal region
  float dacc0 = 0.f, dacc1 = 0.f;

  for (int t = 0; t < nkt; ++t) {
    __syncthreads();
    // stage K tile: 64 rows x 64 d, LDS stride 65
#pragma unroll
    for (int j = 0; j < 2; ++j) {
      int f4 = tid + j * 512;
      int kk = f4 >> 4, d4 = (f4 & 15) << 2;
      float4 v = *(const float4*)&qkv[row_base + (size_t)(t * 64 + kk) * 3072 +
                                      1024 + d4];
      kv_s[kk * 65 + d4 + 0] = v.x;
      kv_s[kk * 65 + d4 + 1] = v.y;
      kv_s[kk * 65 + d4 + 2] = v.z;
      kv_s[kk * 65 + d4 + 3] = v.w;
    }
    __syncthreads();
    float acc0 = 0.f, acc1 = 0.f;
#pragma unroll
    for (int d = 0; d < 64; ++d) {
      float kvv = kv_s[lane * 65 + d];
      acc0 = fmaf(qt[r0 * 64 + d], kvv, acc0);
      acc1 = fmaf(qt[r1 * 64 + d], kvv, acc1);
    }
    int kg = t * 64 + lane;
    float p0 = 0.f, p1 = 0.f;
    if (kg <= qg0) {
      int dist = qg0 - kg;                      // >= 0
      int idx = 32 - (dist > 32 ? 32 : dist);   // clip(k-q,-32,32)+32
      p0 = __expf((acc0 + pj[r0 * 65 + idx]) * 0.125f);
      dacc0 += p0;
    }
    if (kg <= qg1) {
      int dist = qg1 - kg;
      int idx = 32 - (dist > 32 ? 32 : dist);
      p1 = __expf((acc1 + pj[r1 * 65 + idx]) * 0.125f);
      dacc1 += p1;
    }
    p_s[r0 * 2048 + kg] = p0;
    p_s[r1 * 2048 + kg] = p1;
  }

#pragma unroll
  for (int off = 32; off; off >>= 1) {
    dacc0 += __shfl_xor(dacc0, off, 64);
    dacc1 += __shfl_xor(dacc1, off, 64);
  }
  const float inv0 = 1.f / dacc0, inv1 = 1.f / dacc1;

  float* att0 = &att[((size_t)bh * 2048 + qg0) * 2048];
  float* att1 = &att[((size_t)bh * 2048 + qg1) * 2048];

  // zero-fill fully-masked tiles (above causal region)
  for (int t = nkt; t < 32; ++t) {
    att0[t * 64 + lane] = 0.f;
    att1[t * 64 + lane] = 0.f;
  }

  // PV + normalized att writes
  float y0 = 0.f, y1 = 0.f;
  for (int t = 0; t < nkt; ++t) {
    __syncthreads();
#pragma unroll
    for (int j = 0; j < 2; ++j) {
      int f4 = tid + j * 512;
      int kk = f4 >> 4, d4 = (f4 & 15) << 2;
      float4 v = *(const float4*)&qkv[row_base + (size_t)(t * 64 + kk) * 3072 +
                                      2048 + d4];
      kv_s[kk * 65 + d4 + 0] = v.x;
      kv_s[kk * 65 + d4 + 1] = v.y;
      kv_s[kk * 65 + d4 + 2] = v.z;
      kv_s[kk * 65 + d4 + 3] = v.w;
    }
    __syncthreads();
#pragma unroll
    for (int kk = 0; kk < 64; ++kk) {
      float vv = kv_s[kk * 65 + lane];
      y0 = fmaf(p_s[r0 * 2048 + t * 64 + kk], vv, y0);
      y1 = fmaf(p_s[r1 * 2048 + t * 64 + kk], vv, y1);
    }
    att0[t * 64 + lane] = p_s[r0 * 2048 + t * 64 + lane] * inv0;
    att1[t * 64 + lane] = p_s[r1 * 2048 + t * 64 + lane] * inv1;
  }
  ymid[(size_t)(b * 2048 + qg0) * 1024 + h * 64 + lane] = y0 * inv0;
  ymid[(size_t)(b * 2048 + qg1) * 1024 + h * 64 + lane] = y1 * inv1;
}

// ---------------------------------------------------------------------------
extern "C" void kernel_launch(void* const* d_in, const int* in_sizes, int n_in,
                              void* d_out, int out_size, void* d_ws, size_t ws_size,
                              hipStream_t stream) {
  const float* x       = (const float*)d_in[0];
  // d_in[1] = mask (causal tril) -- structure is known, unused
  const float* w_attn  = (const float*)d_in[2];
  const float* b_attn  = (const float*)d_in[3];
  const float* w_proj  = (const float*)d_in[4];
  const float* b_proj  = (const float*)d_in[5];
  const float* rel_tbl = (const float*)d_in[6];

  float* out = (float*)d_out;
  float* att = out + (size_t)2 * 2048 * 1024;          // y first, then att

  float* qkv  = (float*)d_ws;                          // [B,T,3C] 50.3 MB
  float* proj = qkv + (size_t)2 * 2048 * 3072;         // [B,H,T,65] 17 MB
  float* ymid = proj + (size_t)2 * 16 * 2048 * 65;     // [B,T,C] 16.8 MB

  // 1) qkv = x @ w_attn + b_attn
  sgemm_bias_kernel<<<dim3(24, 32), 256, 0, stream>>>(x, w_attn, b_attn, qkv,
                                                      4096, 3072, 1024);
  // 2) rel-position projection (65 distinct relative offsets)
  relproj_kernel<<<16384, 256, 0, stream>>>(qkv, rel_tbl, proj);
  // 3) fused causal attention: att (normalized, full T x T) + y
  attn_kernel<<<dim3(128, 32), 512, 0, stream>>>(qkv, proj, att, ymid);
  // 4) out = y @ w_proj + b_proj
  sgemm_bias_kernel<<<dim3(8, 32), 256, 0, stream>>>(ymid, w_proj, b_proj, out,
                                                     4096, 1024, 1024);
}

// Round 3
// 1777.733 us; speedup vs baseline: 1.2160x; 1.2160x over previous
//
#include <hip/hip_runtime.h>

// Problem constants
// B=2, T=2048, C=1024, H=16, D=64, MAXREL=32
// outputs: y [B,T,C] then att [B,H,T,T], both f32, concatenated in d_out.

// ---------------------------------------------------------------------------
// f32 SGEMM with bias: C[M,N] = A[M,K] @ B[K,N] + bias[N]  (unchanged r1)
// ---------------------------------------------------------------------------
__global__ __launch_bounds__(256)
void sgemm_bias_kernel(const float* __restrict__ A, const float* __restrict__ B,
                       const float* __restrict__ bias, float* __restrict__ C,
                       int M, int N, int K) {
  __shared__ float As[16 * 128];  // transposed: As[k][m]
  __shared__ float Bs[16 * 128];  // Bs[k][n]
  const int tid = threadIdx.x;
  const int tx = tid & 15, ty = tid >> 4;
  const int bm = blockIdx.y * 128, bn = blockIdx.x * 128;

  float acc[8][8] = {{0.f}};

  for (int k0 = 0; k0 < K; k0 += 16) {
#pragma unroll
    for (int j = 0; j < 2; ++j) {
      int f4 = tid + j * 256;
      int m = f4 >> 2, kq = (f4 & 3) << 2;
      float4 va = *(const float4*)&A[(size_t)(bm + m) * K + k0 + kq];
      As[(kq + 0) * 128 + m] = va.x;
      As[(kq + 1) * 128 + m] = va.y;
      As[(kq + 2) * 128 + m] = va.z;
      As[(kq + 3) * 128 + m] = va.w;
      int kr = f4 >> 5, c4 = (f4 & 31) << 2;
      *(float4*)&Bs[kr * 128 + c4] =
          *(const float4*)&B[(size_t)(k0 + kr) * N + bn + c4];
    }
    __syncthreads();
#pragma unroll
    for (int k = 0; k < 16; ++k) {
      float4 a0 = *(const float4*)&As[k * 128 + ty * 4];
      float4 a1 = *(const float4*)&As[k * 128 + 64 + ty * 4];
      float4 b0 = *(const float4*)&Bs[k * 128 + tx * 4];
      float4 b1 = *(const float4*)&Bs[k * 128 + 64 + tx * 4];
      float av[8] = {a0.x, a0.y, a0.z, a0.w, a1.x, a1.y, a1.z, a1.w};
      float bv[8] = {b0.x, b0.y, b0.z, b0.w, b1.x, b1.y, b1.z, b1.w};
#pragma unroll
      for (int i = 0; i < 8; ++i)
#pragma unroll
        for (int j = 0; j < 8; ++j)
          acc[i][j] = fmaf(av[i], bv[j], acc[i][j]);
    }
    __syncthreads();
  }

#pragma unroll
  for (int i = 0; i < 8; ++i) {
    int mrow = bm + ((i < 4) ? (ty * 4 + i) : (64 + ty * 4 + i - 4));
#pragma unroll
    for (int jq = 0; jq < 2; ++jq) {
      int c = bn + jq * 64 + tx * 4;
      float4 o;
      o.x = acc[i][jq * 4 + 0] + bias[c + 0];
      o.y = acc[i][jq * 4 + 1] + bias[c + 1];
      o.z = acc[i][jq * 4 + 2] + bias[c + 2];
      o.w = acc[i][jq * 4 + 3] + bias[c + 3];
      *(float4*)&C[(size_t)mrow * N + c] = o;
    }
  }
}

// ---------------------------------------------------------------------------
// proj[b,h,q,r] = sum_d q[b,h,q,d] * rel_k_table[r,d]   (unchanged r1)
// ---------------------------------------------------------------------------
__global__ __launch_bounds__(256)
void relproj_kernel(const float* __restrict__ qkv, const float* __restrict__ tbl_g,
                    float* __restrict__ proj) {
  __shared__ float tbl[65 * 65];  // [r][d], stride 65
  __shared__ float qsh[4 * 64];
  const int tid = threadIdx.x;
  for (int i = tid; i < 65 * 64; i += 256) {
    int r = i >> 6, d = i & 63;
    tbl[r * 65 + d] = tbl_g[i];
  }
  const int w = tid >> 6, lane = tid & 63;
  const int rid = blockIdx.x * 4 + w;          // (b*16+h)*2048 + q
  const int b = rid >> 15, h = (rid >> 11) & 15, q = rid & 2047;
  qsh[w * 64 + lane] =
      qkv[(size_t)(b * 2048 + q) * 3072 + h * 64 + lane];
  __syncthreads();
  float acc = 0.f;
#pragma unroll
  for (int d = 0; d < 64; ++d)
    acc = fmaf(qsh[w * 64 + d], tbl[lane * 65 + d], acc);
  proj[(size_t)rid * 65 + lane] = acc;
  float part = qsh[w * 64 + lane] * tbl[64 * 65 + lane];
#pragma unroll
  for (int off = 32; off; off >>= 1) part += __shfl_xor(part, off, 64);
  if (lane == 0) proj[(size_t)rid * 65 + 64] = part;
}

// ---------------------------------------------------------------------------
// Fused causal attention v2.
// 512 threads = 8 waves; wave w owns q-rows 2w, 2w+1; lane = k-col / v-dim.
// Changes vs v1:
//  - q rows preloaded into 128 VGPRs (float4 q0v[16]/q1v[16]) - no q LDS reads
//  - QK inner loop: ds_read_b128 on K tile [64][68] (2/bank = conflict floor),
//    8 FMA per read in 4 independent chains
//  - V staged transposed + XOR-swizzled (vT[d][4*(k4^(d&15))]): PV inner loop
//    is 1 b128 v-read + 2 b128 p-broadcasts + 8 FMA per 4 k-cols
// LDS: p_s 128K + kv 17.4K + qt 4K + pj 4.2K = 153.6 KB (1 block/CU, 8 waves).
// ---------------------------------------------------------------------------
__global__ __launch_bounds__(512)
void attn_kernel(const float* __restrict__ qkv, const float* __restrict__ proj,
                 float* __restrict__ att, float* __restrict__ ymid) {
  __shared__ float p_s[16 * 2048];
  __shared__ float kv_s[64 * 68];   // K: [k][d] stride 68; V: swizzled [d][64]
  __shared__ float qt[16 * 64];
  __shared__ float pj[16 * 65];
  const int tid = threadIdx.x;
  const int w = tid >> 6, lane = tid & 63;
  const int bh = blockIdx.y;               // b*16+h
  const int b = bh >> 4, h = bh & 15;
  const int q0 = blockIdx.x << 4;
  const size_t row_base = (size_t)(b * 2048) * 3072 + h * 64;

  if (tid < 256) {
    int r = tid >> 4, c4 = (tid & 15) << 2;
    *(float4*)&qt[r * 64 + c4] =
        *(const float4*)&qkv[row_base + (size_t)(q0 + r) * 3072 + c4];
  }
  {
    const float* psrc = &proj[((size_t)bh * 2048 + q0) * 65];
    for (int i = tid; i < 16 * 65; i += 512) pj[i] = psrc[i];
  }
  __syncthreads();

  const int r0 = w * 2, r1 = r0 + 1;
  const int qg0 = q0 + r0, qg1 = q0 + r1;
  const int nkt = q0 / 64 + 1;  // k-tiles overlapping causal region

  // q rows -> registers (broadcast b128 reads, static indices only)
  float4 q0v[16], q1v[16];
#pragma unroll
  for (int c = 0; c < 16; ++c) {
    q0v[c] = *(float4*)&qt[r0 * 64 + 4 * c];
    q1v[c] = *(float4*)&qt[r1 * 64 + 4 * c];
  }

  // ---------------- QK phase ----------------
  float dacc0 = 0.f, dacc1 = 0.f;
  const float* kbase = qkv + row_base + 1024;
  for (int t = 0; t < nkt; ++t) {
    __syncthreads();
#pragma unroll
    for (int j = 0; j < 2; ++j) {
      int f4 = tid + j * 512;
      int kk = f4 >> 4, d4 = (f4 & 15) << 2;
      *(float4*)&kv_s[kk * 68 + d4] =
          *(const float4*)&kbase[(size_t)(t * 64 + kk) * 3072 + d4];
    }
    __syncthreads();
    float a0a = 0.f, a0b = 0.f, a1a = 0.f, a1b = 0.f;
#pragma unroll
    for (int c = 0; c < 16; ++c) {
      float4 kv = *(float4*)&kv_s[lane * 68 + 4 * c];
      a0a = fmaf(q0v[c].x, kv.x, a0a);
      a0b = fmaf(q0v[c].y, kv.y, a0b);
      a0a = fmaf(q0v[c].z, kv.z, a0a);
      a0b = fmaf(q0v[c].w, kv.w, a0b);
      a1a = fmaf(q1v[c].x, kv.x, a1a);
      a1b = fmaf(q1v[c].y, kv.y, a1b);
      a1a = fmaf(q1v[c].z, kv.z, a1a);
      a1b = fmaf(q1v[c].w, kv.w, a1b);
    }
    float acc0 = a0a + a0b, acc1 = a1a + a1b;
    int kg = t * 64 + lane;
    float p0 = 0.f, p1 = 0.f;
    if (kg <= qg0) {
      int dist = qg0 - kg;
      int idx = 32 - (dist > 32 ? 32 : dist);   // clip(k-q,-32,32)+32
      p0 = __expf((acc0 + pj[r0 * 65 + idx]) * 0.125f);
      dacc0 += p0;
    }
    if (kg <= qg1) {
      int dist = qg1 - kg;
      int idx = 32 - (dist > 32 ? 32 : dist);
      p1 = __expf((acc1 + pj[r1 * 65 + idx]) * 0.125f);
      dacc1 += p1;
    }
    p_s[r0 * 2048 + kg] = p0;
    p_s[r1 * 2048 + kg] = p1;
  }

#pragma unroll
  for (int off = 32; off; off >>= 1) {
    dacc0 += __shfl_xor(dacc0, off, 64);
    dacc1 += __shfl_xor(dacc1, off, 64);
  }
  const float inv0 = 1.f / dacc0, inv1 = 1.f / dacc1;

  float* att0 = &att[((size_t)bh * 2048 + qg0) * 2048];
  float* att1 = &att[((size_t)bh * 2048 + qg1) * 2048];

  // zero-fill fully-masked tiles (above causal region)
  for (int t = nkt; t < 32; ++t) {
    att0[t * 64 + lane] = 0.f;
    att1[t * 64 + lane] = 0.f;
  }

  // ---------------- PV phase ----------------
  const float* vbase = qkv + row_base + 2048;
  float y0a = 0.f, y0b = 0.f, y1a = 0.f, y1b = 0.f;
  for (int t = 0; t < nkt; ++t) {
    __syncthreads();
    // stage V transposed + XOR-swizzled: vT[d][4*(k4^(d&15))+j] = v[4k4+j][d]
#pragma unroll
    for (int j = 0; j < 2; ++j) {
      int idx = tid + j * 512;
      int d = idx & 63, k4 = idx >> 6;
      const float* src = &vbase[(size_t)(t * 64 + 4 * k4) * 3072 + d];
      float4 vv;
      vv.x = src[0];
      vv.y = src[3072];
      vv.z = src[6144];
      vv.w = src[9216];
      *(float4*)&kv_s[d * 64 + 4 * (k4 ^ (d & 15))] = vv;
    }
    __syncthreads();
#pragma unroll
    for (int c = 0; c < 16; ++c) {
      float4 vv = *(float4*)&kv_s[lane * 64 + 4 * (c ^ (lane & 15))];
      float4 pb0 = *(float4*)&p_s[r0 * 2048 + t * 64 + 4 * c];
      float4 pb1 = *(float4*)&p_s[r1 * 2048 + t * 64 + 4 * c];
      y0a = fmaf(pb0.x, vv.x, y0a);
      y0b = fmaf(pb0.y, vv.y, y0b);
      y0a = fmaf(pb0.z, vv.z, y0a);
      y0b = fmaf(pb0.w, vv.w, y0b);
      y1a = fmaf(pb1.x, vv.x, y1a);
      y1b = fmaf(pb1.y, vv.y, y1b);
      y1a = fmaf(pb1.z, vv.z, y1a);
      y1b = fmaf(pb1.w, vv.w, y1b);
    }
    att0[t * 64 + lane] = p_s[r0 * 2048 + t * 64 + lane] * inv0;
    att1[t * 64 + lane] = p_s[r1 * 2048 + t * 64 + lane] * inv1;
  }
  ymid[(size_t)(b * 2048 + qg0) * 1024 + h * 64 + lane] = (y0a + y0b) * inv0;
  ymid[(size_t)(b * 2048 + qg1) * 1024 + h * 64 + lane] = (y1a + y1b) * inv1;
}

// ---------------------------------------------------------------------------
extern "C" void kernel_launch(void* const* d_in, const int* in_sizes, int n_in,
                              void* d_out, int out_size, void* d_ws, size_t ws_size,
                              hipStream_t stream) {
  const float* x       = (const float*)d_in[0];
  // d_in[1] = mask (causal tril) -- structure known, unused
  const float* w_attn  = (const float*)d_in[2];
  const float* b_attn  = (const float*)d_in[3];
  const float* w_proj  = (const float*)d_in[4];
  const float* b_proj  = (const float*)d_in[5];
  const float* rel_tbl = (const float*)d_in[6];

  float* out = (float*)d_out;
  float* att = out + (size_t)2 * 2048 * 1024;          // y first, then att

  float* qkv  = (float*)d_ws;                          // [B,T,3C] 50.3 MB
  float* proj = qkv + (size_t)2 * 2048 * 3072;         // [B,H,T,65] 17 MB
  float* ymid = proj + (size_t)2 * 16 * 2048 * 65;     // [B,T,C] 16.8 MB

  sgemm_bias_kernel<<<dim3(24, 32), 256, 0, stream>>>(x, w_attn, b_attn, qkv,
                                                      4096, 3072, 1024);
  relproj_kernel<<<16384, 256, 0, stream>>>(qkv, rel_tbl, proj);
  attn_kernel<<<dim3(128, 32), 512, 0, stream>>>(qkv, proj, att, ymid);
  sgemm_bias_kernel<<<dim3(8, 32), 256, 0, stream>>>(ymid, w_proj, b_proj, out,
                                                     4096, 1024, 1024);
}

// Round 6
// 1485.480 us; speedup vs baseline: 1.4552x; 1.1967x over previous
//
#include <hip/hip_runtime.h>

// Problem constants
// B=2, T=2048, C=1024, H=16, D=64, MAXREL=32
// outputs: y [B,T,C] then att [B,H,T,T], both f32, concatenated in d_out.

typedef __bf16 bf16x8 __attribute__((ext_vector_type(8)));
typedef float f32x4 __attribute__((ext_vector_type(4)));
typedef unsigned short u16x8 __attribute__((ext_vector_type(8)));

// f32 -> bf16 (RNE) and back, bit-level (no header dependency)
__device__ __forceinline__ unsigned short f2bf(float f) {
  unsigned u = __float_as_uint(f);
  u += 0x7fff + ((u >> 16) & 1);
  return (unsigned short)(u >> 16);
}
__device__ __forceinline__ float bf2f(unsigned short s) {
  return __uint_as_float(((unsigned)s) << 16);
}

// ---------------------------------------------------------------------------
// cvt_split: f32[n] -> hi bf16[n], lo bf16[n]   (a ~= hi + lo, each bf16)
// one float4 per thread.
// ---------------------------------------------------------------------------
__global__ __launch_bounds__(256)
void cvt_split(const float* __restrict__ in, unsigned short* __restrict__ hi,
               unsigned short* __restrict__ lo, int n4) {
  int i = blockIdx.x * 256 + threadIdx.x;
  if (i >= n4) return;
  float4 v = ((const float4*)in)[i];
  ushort4 h, l;
  h.x = f2bf(v.x); l.x = f2bf(v.x - bf2f(h.x));
  h.y = f2bf(v.y); l.y = f2bf(v.y - bf2f(h.y));
  h.z = f2bf(v.z); l.z = f2bf(v.z - bf2f(h.z));
  h.w = f2bf(v.w); l.w = f2bf(v.w - bf2f(h.w));
  ((ushort4*)hi)[i] = h;
  ((ushort4*)lo)[i] = l;
}

// ---------------------------------------------------------------------------
// cvt_split_T: in f32[K][N] -> hiT,loT bf16[N][K]  (transpose via LDS tile)
// 64x64 tile, 256 threads.
// ---------------------------------------------------------------------------
__global__ __launch_bounds__(256)
void cvt_split_T(const float* __restrict__ in, unsigned short* __restrict__ hiT,
                 unsigned short* __restrict__ loT, int K, int N) {
  __shared__ float tile[64][65];
  const int tid = threadIdx.x;
  const int bc = blockIdx.x * 64;  // n block
  const int br = blockIdx.y * 64;  // k block
#pragma unroll
  for (int j = 0; j < 4; ++j) {
    int f = tid + j * 256;
    int r = f >> 4, c4 = (f & 15) << 2;
    *(float4*)&tile[r][c4] = *(const float4*)&in[(size_t)(br + r) * N + bc + c4];
  }
  __syncthreads();
#pragma unroll
  for (int j = 0; j < 4; ++j) {
    int f = tid + j * 256;
    int n = f >> 4, k4 = (f & 15) << 2;
    ushort4 h, l;
    float v;
    v = tile[k4 + 0][n]; h.x = f2bf(v); l.x = f2bf(v - bf2f(h.x));
    v = tile[k4 + 1][n]; h.y = f2bf(v); l.y = f2bf(v - bf2f(h.y));
    v = tile[k4 + 2][n]; h.z = f2bf(v); l.z = f2bf(v - bf2f(h.z));
    v = tile[k4 + 3][n]; h.w = f2bf(v); l.w = f2bf(v - bf2f(h.w));
    size_t o = (size_t)(bc + n) * K + br + k4;
    *(ushort4*)&hiT[o] = h;
    *(ushort4*)&loT[o] = l;
  }
}

// ---------------------------------------------------------------------------
// Split-bf16 MFMA GEMM: C[M,N] = A[M,K] @ B[K,N] + bias, near-f32 accuracy.
// A given as Ah/Al bf16 [M][K]; B given TRANSPOSED as Bth/Btl bf16 [N][K].
// 128x128 tile, BK=32, 256 threads = 4 waves (each one 64x64 quadrant).
// Per k-step per wave: 16 frag loads (b128), 48 mfma_f32_16x16x32_bf16
// (hi*hi + hi*lo + lo*hi). LDS 16B-chunk XOR swizzle (2-way = free).
// Reg-prefetch: next tile's global loads issued before the MFMA block.
// ---------------------------------------------------------------------------
__device__ __forceinline__ int swz(int row, int k) {
  // element index into [row][32] bf16 with 16B-chunk swizzle
  return row * 32 + ((((k >> 3) ^ row) & 3) << 3) + (k & 7);
}

__global__ __launch_bounds__(256)
void mfma_gemm_bias(const unsigned short* __restrict__ Ah,
                    const unsigned short* __restrict__ Al,
                    const unsigned short* __restrict__ Bth,
                    const unsigned short* __restrict__ Btl,
                    const float* __restrict__ bias, float* __restrict__ C,
                    int M, int N, int K) {
  __shared__ unsigned short As_h[128 * 32], As_l[128 * 32];
  __shared__ unsigned short Bs_h[128 * 32], Bs_l[128 * 32];
  const int tid = threadIdx.x;
  const int bm = blockIdx.y * 128, bn = blockIdx.x * 128;
  const int l = tid & 63, w = tid >> 6;
  const int wm = (w >> 1) * 64, wn = (w & 1) * 64;
  const int fr = l & 15, kg = (l >> 4) << 3;

  // staging indices: 2 u16x8 units per matrix per thread
  const int u0 = tid, u1 = tid + 256;
  const int m0s = u0 >> 2, k0s = (u0 & 3) << 3;
  const int m1s = u1 >> 2, k1s = (u1 & 3) << 3;

  f32x4 acc[4][4];
#pragma unroll
  for (int i = 0; i < 4; ++i)
#pragma unroll
    for (int j = 0; j < 4; ++j) {
      acc[i][j].x = 0.f; acc[i][j].y = 0.f; acc[i][j].z = 0.f; acc[i][j].w = 0.f;
    }

  u16x8 rah0, rah1, ral0, ral1, rbh0, rbh1, rbl0, rbl1;
  // prologue: load k-step 0
  {
    const size_t a0 = (size_t)(bm + m0s) * K + k0s, a1 = (size_t)(bm + m1s) * K + k1s;
    const size_t b0 = (size_t)(bn + m0s) * K + k0s, b1 = (size_t)(bn + m1s) * K + k1s;
    rah0 = *(const u16x8*)&Ah[a0];  rah1 = *(const u16x8*)&Ah[a1];
    ral0 = *(const u16x8*)&Al[a0];  ral1 = *(const u16x8*)&Al[a1];
    rbh0 = *(const u16x8*)&Bth[b0]; rbh1 = *(const u16x8*)&Bth[b1];
    rbl0 = *(const u16x8*)&Btl[b0]; rbl1 = *(const u16x8*)&Btl[b1];
  }

  const int nk = K >> 5;
  for (int ks = 0; ks < nk; ++ks) {
    __syncthreads();  // previous compute done reading LDS
    *(u16x8*)&As_h[swz(m0s, k0s)] = rah0;  *(u16x8*)&As_h[swz(m1s, k1s)] = rah1;
    *(u16x8*)&As_l[swz(m0s, k0s)] = ral0;  *(u16x8*)&As_l[swz(m1s, k1s)] = ral1;
    *(u16x8*)&Bs_h[swz(m0s, k0s)] = rbh0;  *(u16x8*)&Bs_h[swz(m1s, k1s)] = rbh1;
    *(u16x8*)&Bs_l[swz(m0s, k0s)] = rbl0;  *(u16x8*)&Bs_l[swz(m1s, k1s)] = rbl1;
    __syncthreads();
    if (ks + 1 < nk) {  // issue next-tile loads; latency hides under MFMAs
      const int k0 = (ks + 1) << 5;
      const size_t a0 = (size_t)(bm + m0s) * K + k0 + k0s,
                   a1 = (size_t)(bm + m1s) * K + k0 + k1s;
      const size_t b0 = (size_t)(bn + m0s) * K + k0 + k0s,
                   b1 = (size_t)(bn + m1s) * K + k0 + k1s;
      rah0 = *(const u16x8*)&Ah[a0];  rah1 = *(const u16x8*)&Ah[a1];
      ral0 = *(const u16x8*)&Al[a0];  ral1 = *(const u16x8*)&Al[a1];
      rbh0 = *(const u16x8*)&Bth[b0]; rbh1 = *(const u16x8*)&Bth[b1];
      rbl0 = *(const u16x8*)&Btl[b0]; rbl1 = *(const u16x8*)&Btl[b1];
    }
    bf16x8 ah[4], al[4], bh[4], bl[4];
#pragma unroll
    for (int i = 0; i < 4; ++i) {
      ah[i] = *(bf16x8*)&As_h[swz(wm + i * 16 + fr, kg)];
      al[i] = *(bf16x8*)&As_l[swz(wm + i * 16 + fr, kg)];
      bh[i] = *(bf16x8*)&Bs_h[swz(wn + i * 16 + fr, kg)];
      bl[i] = *(bf16x8*)&Bs_l[swz(wn + i * 16 + fr, kg)];
    }
#pragma unroll
    for (int mi = 0; mi < 4; ++mi)
#pragma unroll
      for (int ni = 0; ni < 4; ++ni) {
        acc[mi][ni] = __builtin_amdgcn_mfma_f32_16x16x32_bf16(
            ah[mi], bh[ni], acc[mi][ni], 0, 0, 0);
        acc[mi][ni] = __builtin_amdgcn_mfma_f32_16x16x32_bf16(
            ah[mi], bl[ni], acc[mi][ni], 0, 0, 0);
        acc[mi][ni] = __builtin_amdgcn_mfma_f32_16x16x32_bf16(
            al[mi], bh[ni], acc[mi][ni], 0, 0, 0);
      }
  }

  // epilogue: C/D layout col=lane&15, row=(lane>>4)*4+j  (m89-verified)
#pragma unroll
  for (int mi = 0; mi < 4; ++mi) {
    const int rowb = bm + wm + mi * 16 + (l >> 4) * 4;
#pragma unroll
    for (int ni = 0; ni < 4; ++ni) {
      const int col = bn + wn + ni * 16 + fr;
      const float bv = bias[col];
      C[(size_t)(rowb + 0) * N + col] = acc[mi][ni].x + bv;
      C[(size_t)(rowb + 1) * N + col] = acc[mi][ni].y + bv;
      C[(size_t)(rowb + 2) * N + col] = acc[mi][ni].z + bv;
      C[(size_t)(rowb + 3) * N + col] = acc[mi][ni].w + bv;
    }
  }
}

// ---------------------------------------------------------------------------
// proj[b,h,q,r] = sum_d q[b,h,q,d] * rel_k_table[r,d]   (unchanged)
// ---------------------------------------------------------------------------
__global__ __launch_bounds__(256)
void relproj_kernel(const float* __restrict__ qkv, const float* __restrict__ tbl_g,
                    float* __restrict__ proj) {
  __shared__ float tbl[65 * 65];  // [r][d], stride 65
  __shared__ float qsh[4 * 64];
  const int tid = threadIdx.x;
  for (int i = tid; i < 65 * 64; i += 256) {
    int r = i >> 6, d = i & 63;
    tbl[r * 65 + d] = tbl_g[i];
  }
  const int w = tid >> 6, lane = tid & 63;
  const int rid = blockIdx.x * 4 + w;          // (b*16+h)*2048 + q
  const int b = rid >> 15, h = (rid >> 11) & 15, q = rid & 2047;
  qsh[w * 64 + lane] =
      qkv[(size_t)(b * 2048 + q) * 3072 + h * 64 + lane];
  __syncthreads();
  float acc = 0.f;
#pragma unroll
  for (int d = 0; d < 64; ++d)
    acc = fmaf(qsh[w * 64 + d], tbl[lane * 65 + d], acc);
  proj[(size_t)rid * 65 + lane] = acc;
  float part = qsh[w * 64 + lane] * tbl[64 * 65 + lane];
#pragma unroll
  for (int off = 32; off; off >>= 1) part += __shfl_xor(part, off, 64);
  if (lane == 0) proj[(size_t)rid * 65 + 64] = part;
}

// ---------------------------------------------------------------------------
// Fused causal attention (unchanged from round 3 - passed, 920us)
// ---------------------------------------------------------------------------
__global__ __launch_bounds__(512)
void attn_kernel(const float* __restrict__ qkv, const float* __restrict__ proj,
                 float* __restrict__ att, float* __restrict__ ymid) {
  __shared__ float p_s[16 * 2048];
  __shared__ float kv_s[64 * 68];   // K: [k][d] stride 68; V: swizzled [d][64]
  __shared__ float qt[16 * 64];
  __shared__ float pj[16 * 65];
  const int tid = threadIdx.x;
  const int w = tid >> 6, lane = tid & 63;
  const int bh = blockIdx.y;               // b*16+h
  const int b = bh >> 4, h = bh & 15;
  const int q0 = blockIdx.x << 4;
  const size_t row_base = (size_t)(b * 2048) * 3072 + h * 64;

  if (tid < 256) {
    int r = tid >> 4, c4 = (tid & 15) << 2;
    *(float4*)&qt[r * 64 + c4] =
        *(const float4*)&qkv[row_base + (size_t)(q0 + r) * 3072 + c4];
  }
  {
    const float* psrc = &proj[((size_t)bh * 2048 + q0) * 65];
    for (int i = tid; i < 16 * 65; i += 512) pj[i] = psrc[i];
  }
  __syncthreads();

  const int r0 = w * 2, r1 = r0 + 1;
  const int qg0 = q0 + r0, qg1 = q0 + r1;
  const int nkt = q0 / 64 + 1;  // k-tiles overlapping causal region

  float4 q0v[16], q1v[16];
#pragma unroll
  for (int c = 0; c < 16; ++c) {
    q0v[c] = *(float4*)&qt[r0 * 64 + 4 * c];
    q1v[c] = *(float4*)&qt[r1 * 64 + 4 * c];
  }

  // ---------------- QK phase ----------------
  float dacc0 = 0.f, dacc1 = 0.f;
  const float* kbase = qkv + row_base + 1024;
  for (int t = 0; t < nkt; ++t) {
    __syncthreads();
#pragma unroll
    for (int j = 0; j < 2; ++j) {
      int f4 = tid + j * 512;
      int kk = f4 >> 4, d4 = (f4 & 15) << 2;
      *(float4*)&kv_s[kk * 68 + d4] =
          *(const float4*)&kbase[(size_t)(t * 64 + kk) * 3072 + d4];
    }
    __syncthreads();
    float a0a = 0.f, a0b = 0.f, a1a = 0.f, a1b = 0.f;
#pragma unroll
    for (int c = 0; c < 16; ++c) {
      float4 kv = *(float4*)&kv_s[lane * 68 + 4 * c];
      a0a = fmaf(q0v[c].x, kv.x, a0a);
      a0b = fmaf(q0v[c].y, kv.y, a0b);
      a0a = fmaf(q0v[c].z, kv.z, a0a);
      a0b = fmaf(q0v[c].w, kv.w, a0b);
      a1a = fmaf(q1v[c].x, kv.x, a1a);
      a1b = fmaf(q1v[c].y, kv.y, a1b);
      a1a = fmaf(q1v[c].z, kv.z, a1a);
      a1b = fmaf(q1v[c].w, kv.w, a1b);
    }
    float acc0 = a0a + a0b, acc1 = a1a + a1b;
    int kg = t * 64 + lane;
    float p0 = 0.f, p1 = 0.f;
    if (kg <= qg0) {
      int dist = qg0 - kg;
      int idx = 32 - (dist > 32 ? 32 : dist);   // clip(k-q,-32,32)+32
      p0 = __expf((acc0 + pj[r0 * 65 + idx]) * 0.125f);
      dacc0 += p0;
    }
    if (kg <= qg1) {
      int dist = qg1 - kg;
      int idx = 32 - (dist > 32 ? 32 : dist);
      p1 = __expf((acc1 + pj[r1 * 65 + idx]) * 0.125f);
      dacc1 += p1;
    }
    p_s[r0 * 2048 + kg] = p0;
    p_s[r1 * 2048 + kg] = p1;
  }

#pragma unroll
  for (int off = 32; off; off >>= 1) {
    dacc0 += __shfl_xor(dacc0, off, 64);
    dacc1 += __shfl_xor(dacc1, off, 64);
  }
  const float inv0 = 1.f / dacc0, inv1 = 1.f / dacc1;

  float* att0 = &att[((size_t)bh * 2048 + qg0) * 2048];
  float* att1 = &att[((size_t)bh * 2048 + qg1) * 2048];

  for (int t = nkt; t < 32; ++t) {
    att0[t * 64 + lane] = 0.f;
    att1[t * 64 + lane] = 0.f;
  }

  // ---------------- PV phase ----------------
  const float* vbase = qkv + row_base + 2048;
  float y0a = 0.f, y0b = 0.f, y1a = 0.f, y1b = 0.f;
  for (int t = 0; t < nkt; ++t) {
    __syncthreads();
#pragma unroll
    for (int j = 0; j < 2; ++j) {
      int idx = tid + j * 512;
      int d = idx & 63, k4 = idx >> 6;
      const float* src = &vbase[(size_t)(t * 64 + 4 * k4) * 3072 + d];
      float4 vv;
      vv.x = src[0];
      vv.y = src[3072];
      vv.z = src[6144];
      vv.w = src[9216];
      *(float4*)&kv_s[d * 64 + 4 * (k4 ^ (d & 15))] = vv;
    }
    __syncthreads();
#pragma unroll
    for (int c = 0; c < 16; ++c) {
      float4 vv = *(float4*)&kv_s[lane * 64 + 4 * (c ^ (lane & 15))];
      float4 pb0 = *(float4*)&p_s[r0 * 2048 + t * 64 + 4 * c];
      float4 pb1 = *(float4*)&p_s[r1 * 2048 + t * 64 + 4 * c];
      y0a = fmaf(pb0.x, vv.x, y0a);
      y0b = fmaf(pb0.y, vv.y, y0b);
      y0a = fmaf(pb0.z, vv.z, y0a);
      y0b = fmaf(pb0.w, vv.w, y0b);
      y1a = fmaf(pb1.x, vv.x, y1a);
      y1b = fmaf(pb1.y, vv.y, y1b);
      y1a = fmaf(pb1.z, vv.z, y1a);
      y1b = fmaf(pb1.w, vv.w, y1b);
    }
    att0[t * 64 + lane] = p_s[r0 * 2048 + t * 64 + lane] * inv0;
    att1[t * 64 + lane] = p_s[r1 * 2048 + t * 64 + lane] * inv1;
  }
  ymid[(size_t)(b * 2048 + qg0) * 1024 + h * 64 + lane] = (y0a + y0b) * inv0;
  ymid[(size_t)(b * 2048 + qg1) * 1024 + h * 64 + lane] = (y1a + y1b) * inv1;
}

// ---------------------------------------------------------------------------
extern "C" void kernel_launch(void* const* d_in, const int* in_sizes, int n_in,
                              void* d_out, int out_size, void* d_ws, size_t ws_size,
                              hipStream_t stream) {
  const float* x       = (const float*)d_in[0];
  // d_in[1] = mask (causal tril) -- structure known, unused
  const float* w_attn  = (const float*)d_in[2];
  const float* b_attn  = (const float*)d_in[3];
  const float* w_proj  = (const float*)d_in[4];
  const float* b_proj  = (const float*)d_in[5];
  const float* rel_tbl = (const float*)d_in[6];

  float* out = (float*)d_out;
  float* att = out + (size_t)2 * 2048 * 1024;          // y first, then att

  // workspace layout (f32 then bf16/ushort), ~118 MB total
  float* qkv  = (float*)d_ws;                          // 12,582,912 f32
  float* proj = qkv + (size_t)12582912;                // 4,259,840 f32
  float* ymid = proj + (size_t)4259840;                // 4,194,304 f32
  unsigned short* xh  = (unsigned short*)(ymid + (size_t)4194304);
  unsigned short* xl  = xh + (size_t)4194304;          // (reused for ymid hi/lo)
  unsigned short* wah = xl + (size_t)4194304;
  unsigned short* wal = wah + (size_t)3145728;
  unsigned short* wph = wal + (size_t)3145728;
  unsigned short* wpl = wph + (size_t)1048576;

  // 0) split-precision conversions
  cvt_split<<<4096, 256, 0, stream>>>(x, xh, xl, 1048576);
  cvt_split_T<<<dim3(48, 16), 256, 0, stream>>>(w_attn, wah, wal, 1024, 3072);
  cvt_split_T<<<dim3(16, 16), 256, 0, stream>>>(w_proj, wph, wpl, 1024, 1024);

  // 1) qkv = x @ w_attn + b_attn   (split-bf16 MFMA)
  mfma_gemm_bias<<<dim3(24, 32), 256, 0, stream>>>(xh, xl, wah, wal, b_attn,
                                                   qkv, 4096, 3072, 1024);
  // 2) rel-position projection
  relproj_kernel<<<16384, 256, 0, stream>>>(qkv, rel_tbl, proj);
  // 3) fused causal attention
  attn_kernel<<<dim3(128, 32), 512, 0, stream>>>(qkv, proj, att, ymid);
  // 4) out = ymid @ w_proj + b_proj   (split-bf16 MFMA)
  cvt_split<<<4096, 256, 0, stream>>>(ymid, xh, xl, 1048576);
  mfma_gemm_bias<<<dim3(8, 32), 256, 0, stream>>>(xh, xl, wph, wpl, b_proj,
                                                  out, 4096, 1024, 1024);
}